// Round 4
// baseline (169.599 us; speedup 1.0000x reference)
//
#include <hip/hip_runtime.h>
#include <hip/hip_bf16.h>

typedef __attribute__((ext_vector_type(4))) float f32x4;
typedef __attribute__((ext_vector_type(8))) short short8v;
typedef __attribute__((ext_vector_type(4))) unsigned short ushort4v;

#define T_ROWS 16384
#define H_DIM  4096
#define E_NUM  64
#define TOPK   8
#define NKS    (H_DIM / 32)   // 128 k-steps of 32

__device__ __forceinline__ unsigned short f2bf(float f) {
    unsigned int u = __float_as_uint(f);
    unsigned int r = (u + 0x7fffu + ((u >> 16) & 1u)) >> 16;  // RNE
    return (unsigned short)r;
}
__device__ __forceinline__ float bf2f(unsigned short h) {
    return __uint_as_float(((unsigned int)h) << 16);
}

// ---- prep: split W f32 [64][4096] into bf16 hi/lo planes in d_ws ----
__global__ __launch_bounds__(256) void prep_w(
    const float* __restrict__ W, unsigned short* __restrict__ WH,
    unsigned short* __restrict__ WL)
{
    const int i = (blockIdx.x * 256 + threadIdx.x) * 4;   // grid 256 -> 262144 elems
    const float4 v = *(const float4*)(W + i);
    float f[4] = {v.x, v.y, v.z, v.w};
    ushort4v h, l;
#pragma unroll
    for (int j = 0; j < 4; ++j) {
        unsigned short hb = f2bf(f[j]);
        h[j] = hb;
        l[j] = f2bf(f[j] - bf2f(hb));
    }
    *(ushort4v*)(WH + i) = h;
    *(ushort4v*)(WL + i) = l;
}

// ---- main: 1 wave = 16 rows x 64 experts, no LDS, no barriers ----
__global__ __launch_bounds__(64) void router_main(
    const float* __restrict__ X, const unsigned short* __restrict__ WH,
    const unsigned short* __restrict__ WL, const int* __restrict__ ids,
    int nids, float* __restrict__ out)
{
    const int lane = threadIdx.x & 63;
    const int rb   = blockIdx.x * 16;
    const int fr   = lane & 15;
    const int fq   = lane >> 4;

    // allowed-expert bitmask (uniform across lanes; scalar-cached loads)
    unsigned long long mbits = 0;
    for (int t = 0; t < nids; ++t) {
        const int e = ids[t];
        if (e >= 0 && e < E_NUM) mbits |= (1ull << e);
    }

    const float*          xp  = X  + (size_t)(rb + fr) * H_DIM + fq * 8;
    const unsigned short* wh0 = WH + (size_t)fr * H_DIM + fq * 8;
    const unsigned short* wl0 = WL + (size_t)fr * H_DIM + fq * 8;

    f32x4 acc0 = {0.f,0.f,0.f,0.f};
    f32x4 acc1 = acc0, acc2 = acc0, acc3 = acc0;

    float4 pa = *(const float4*)(xp);
    float4 pb = *(const float4*)(xp + 4);

    auto body = [&](float4 ca, float4 cb, int ko) {
        // B-frags for 4 expert groups (bf16 hi/lo, L2-resident)
        short8v bh0 = *(const short8v*)(wh0 +  0 * H_DIM + ko);
        short8v bh1 = *(const short8v*)(wh0 + 16 * H_DIM + ko);
        short8v bh2 = *(const short8v*)(wh0 + 32 * H_DIM + ko);
        short8v bh3 = *(const short8v*)(wh0 + 48 * H_DIM + ko);
        short8v bl0 = *(const short8v*)(wl0 +  0 * H_DIM + ko);
        short8v bl1 = *(const short8v*)(wl0 + 16 * H_DIM + ko);
        short8v bl2 = *(const short8v*)(wl0 + 32 * H_DIM + ko);
        short8v bl3 = *(const short8v*)(wl0 + 48 * H_DIM + ko);
        // A-frag: split 8 f32 into bf16 hi/lo in-register
        float v[8] = {ca.x, ca.y, ca.z, ca.w, cb.x, cb.y, cb.z, cb.w};
        short8v ah, al;
#pragma unroll
        for (int j = 0; j < 8; ++j) {
            unsigned short hb = f2bf(v[j]);
            ah[j] = (short)hb;
            al[j] = (short)f2bf(v[j] - bf2f(hb));
        }
        acc0 = __builtin_amdgcn_mfma_f32_16x16x32_bf16(ah, bh0, acc0, 0, 0, 0);
        acc0 = __builtin_amdgcn_mfma_f32_16x16x32_bf16(ah, bl0, acc0, 0, 0, 0);
        acc0 = __builtin_amdgcn_mfma_f32_16x16x32_bf16(al, bh0, acc0, 0, 0, 0);
        acc1 = __builtin_amdgcn_mfma_f32_16x16x32_bf16(ah, bh1, acc1, 0, 0, 0);
        acc1 = __builtin_amdgcn_mfma_f32_16x16x32_bf16(ah, bl1, acc1, 0, 0, 0);
        acc1 = __builtin_amdgcn_mfma_f32_16x16x32_bf16(al, bh1, acc1, 0, 0, 0);
        acc2 = __builtin_amdgcn_mfma_f32_16x16x32_bf16(ah, bh2, acc2, 0, 0, 0);
        acc2 = __builtin_amdgcn_mfma_f32_16x16x32_bf16(ah, bl2, acc2, 0, 0, 0);
        acc2 = __builtin_amdgcn_mfma_f32_16x16x32_bf16(al, bh2, acc2, 0, 0, 0);
        acc3 = __builtin_amdgcn_mfma_f32_16x16x32_bf16(ah, bh3, acc3, 0, 0, 0);
        acc3 = __builtin_amdgcn_mfma_f32_16x16x32_bf16(ah, bl3, acc3, 0, 0, 0);
        acc3 = __builtin_amdgcn_mfma_f32_16x16x32_bf16(al, bh3, acc3, 0, 0, 0);
    };

#pragma unroll 2
    for (int ch = 0; ch < NKS - 1; ++ch) {
        const float4 ca = pa, cb = pb;
        // prefetch next k-step's X (keeps HBM stream in flight; no barriers to drain)
        pa = *(const float4*)(xp + (ch + 1) * 32);
        pb = *(const float4*)(xp + (ch + 1) * 32 + 4);
        body(ca, cb, ch * 32);
    }
    body(pa, pb, (NKS - 1) * 32);

    // ---- epilogue: mask, logits (f32), softmax + top-8 + renorm ----
    // C/D layout: col = lane&15, row_in_16 = (lane>>4)*4 + reg  (value-verified r2/r3)
    float* o_log = out;
    float* o_rw  = out + (size_t)T_ROWS * E_NUM;
    float* o_se  = o_rw + (size_t)T_ROWS * TOPK;

#pragma unroll
    for (int j = 0; j < 4; ++j) {
        const int grow = rb + fq * 4 + j;
        float mv0 = ((mbits >> ( 0 + fr)) & 1) ? acc0[j] : -10000.0f;
        float mv1 = ((mbits >> (16 + fr)) & 1) ? acc1[j] : -10000.0f;
        float mv2 = ((mbits >> (32 + fr)) & 1) ? acc2[j] : -10000.0f;
        float mv3 = ((mbits >> (48 + fr)) & 1) ? acc3[j] : -10000.0f;
        o_log[(size_t)grow * 64 +  0 + fr] = mv0;
        o_log[(size_t)grow * 64 + 16 + fr] = mv1;
        o_log[(size_t)grow * 64 + 32 + fr] = mv2;
        o_log[(size_t)grow * 64 + 48 + fr] = mv3;

        float m = fmaxf(fmaxf(mv0, mv1), fmaxf(mv2, mv3));
#pragma unroll
        for (int off = 1; off < 16; off <<= 1) m = fmaxf(m, __shfl_xor(m, off));

        float tsum = 0.f, myv = 0.f;
        int   mye  = 0;
#pragma unroll
        for (int t = 0; t < TOPK; ++t) {
            float bv = mv0; int be = fr;
            if (mv1 > bv) { bv = mv1; be = 16 + fr; }
            if (mv2 > bv) { bv = mv2; be = 32 + fr; }
            if (mv3 > bv) { bv = mv3; be = 48 + fr; }
#pragma unroll
            for (int off = 1; off < 16; off <<= 1) {
                float ov = __shfl_xor(bv, off);
                int   oe = __shfl_xor(be, off);
                if (ov > bv || (ov == bv && oe < be)) { bv = ov; be = oe; }
            }
            const float pv = expf(bv - m);
            tsum += pv;
            if (fr == t) { myv = pv; mye = be; }
            if ((be & 15) == fr) {       // owner lane excludes the winner
                const int bn = be >> 4;
                if      (bn == 0) mv0 = -3.4e38f;
                else if (bn == 1) mv1 = -3.4e38f;
                else if (bn == 2) mv2 = -3.4e38f;
                else              mv3 = -3.4e38f;
            }
        }
        if (fr < TOPK) {
            o_rw[(size_t)grow * TOPK + fr] = myv / tsum;
            o_se[(size_t)grow * TOPK + fr] = (float)mye;
        }
    }
}

extern "C" void kernel_launch(void* const* d_in, const int* in_sizes, int n_in,
                              void* d_out, int out_size, void* d_ws, size_t ws_size,
                              hipStream_t stream) {
    const float* X   = (const float*)d_in[0];
    const float* W   = (const float*)d_in[1];
    const int*   ids = (const int*)d_in[2];
    const int    nids = in_sizes[2];
    float* out = (float*)d_out;

    unsigned short* WH = (unsigned short*)d_ws;                       // 512 KB
    unsigned short* WL = WH + (size_t)E_NUM * H_DIM;                  // 512 KB

    hipLaunchKernelGGL(prep_w, dim3(E_NUM * H_DIM / 1024), dim3(256), 0, stream, W, WH, WL);
    hipLaunchKernelGGL(router_main, dim3(T_ROWS / 16), dim3(64), 0, stream,
                       X, WH, WL, ids, nids, out);
}